// Round 12
// baseline (151.009 us; speedup 1.0000x reference)
//
#include <hip/hip_runtime.h>
#include <hip/hip_bf16.h>

// VectorQuantizer: x [32768 x 64] fp32, e [64 x 1024] fp32.
// d_out = [out (2097152 f32) = x + (q-x), loss = 1.25*mean((q-x)^2)].
//
// R12: R11's clean-allocation shape (block = 32 rows, 2 M-tiles/wave, wave
// owns a 256-code K-slice, grid 1024, waves_per_eu(4,4)) with three changes:
//  (a) K-loop rebuilt as a MANUAL 4-deep named-slot software pipeline
//      (nt += 4, four explicit bodies, constant slot indices) so each body's
//      s_waitcnt covers only its own slot's 4 loads — 4-iteration prefetch
//      lead instead of the array-ring whose waits serialized every iter
//      (R11: ~7000 cyc/iter at 9% MfmaUtil despite zero spills).
//  (b) se staged to LDS (ds_read replaces the 5th global load in the chain).
//  (c) loss via per-block parts[] (no 1024-deep same-address atomic chain);
//      vq_fix's ticket-last block sums parts + rare exact-recheck deltas.
// Numerics unchanged from the validated path: 6-MFMA bf16x3-split keys
// (se - 2*dot), strict < + earliest-k tie-break, MARGIN flag list, R9's
// exact-fp32 parallel vq_fix (R1-validated ascending-fmaf math).

#define NROWS 32768
#define DDIM  64
#define KCODE 1024
#define NELEM (NROWS * DDIM)
#define MARGIN 2.5e-4f
#define FIXBLOCKS 256
#define MAINBLK 1024

typedef __attribute__((ext_vector_type(8))) short bf16x8;
typedef __attribute__((ext_vector_type(4))) float f32x4;

static __device__ __forceinline__ unsigned short f2bf(float v) {
    __hip_bfloat16 h = __float2bfloat16(v);
    unsigned short b;
    __builtin_memcpy(&b, &h, 2);
    return b;
}
static __device__ __forceinline__ float bf2f(unsigned short b) {
    unsigned int u = ((unsigned int)b) << 16;
    float f;
    __builtin_memcpy(&f, &u, 4);
    return f;
}

// ---------------------------------------------------------------------------
// prep (64 blocks x 256): per block 16 codes. se[k] exact fp32 (ascending-d
// fmaf — must match vq_fix), eT[k][d] fp32, ehT/elT[k][d] bf16 hi/lo.
__global__ void vq_prep(const float* __restrict__ e,
                        float* __restrict__ se,
                        float* __restrict__ eT,
                        unsigned short* __restrict__ ehT,
                        unsigned short* __restrict__ elT,
                        int* __restrict__ ctrl) {
    __shared__ float tile[64][17];
    const int t = threadIdx.x;
    const int k0 = blockIdx.x * 16;
    if (blockIdx.x == 0 && t < 4) ctrl[t] = 0;
    #pragma unroll
    for (int i = 0; i < 4; ++i) {
        int idx = i * 256 + t;
        int d = idx >> 4, kk = idx & 15;
        tile[d][kk] = e[d * KCODE + k0 + kk];
    }
    __syncthreads();
    if (t < 16) {
        float s = 0.f;
        #pragma unroll
        for (int d = 0; d < 64; ++d) { float v = tile[d][t]; s = fmaf(v, v, s); }
        se[k0 + t] = s;
    }
    const int kk = t >> 4;           // code 0..15
    const int dg = (t & 15) * 4;     // dim chunk
    float v0 = tile[dg + 0][kk], v1 = tile[dg + 1][kk];
    float v2 = tile[dg + 2][kk], v3 = tile[dg + 3][kk];
    *(float4*)&eT[(size_t)(k0 + kk) * 64 + dg] = make_float4(v0, v1, v2, v3);
    unsigned short h0 = f2bf(v0), h1 = f2bf(v1), h2 = f2bf(v2), h3 = f2bf(v3);
    *(ushort4*)&ehT[(size_t)(k0 + kk) * 64 + dg] = make_ushort4(h0, h1, h2, h3);
    *(ushort4*)&elT[(size_t)(k0 + kk) * 64 + dg] =
        make_ushort4(f2bf(v0 - bf2f(h0)), f2bf(v1 - bf2f(h1)),
                     f2bf(v2 - bf2f(h2)), f2bf(v3 - bf2f(h3)));
}

// ---------------------------------------------------------------------------
__attribute__((amdgpu_waves_per_eu(4, 4)))
__launch_bounds__(256)
__global__ void vq_main(const float* __restrict__ x,
                        const float* __restrict__ se,
                        const float* __restrict__ eT,
                        const unsigned short* __restrict__ ehT,
                        const unsigned short* __restrict__ elT,
                        float* __restrict__ out,
                        float* __restrict__ parts,
                        int* __restrict__ cnt,
                        int2* __restrict__ list) {
    __shared__ float sse[KCODE];          // 4 KB
    __shared__ float Lb [32][65];
    __shared__ float Lb2[32][65];
    __shared__ int   Li [32][65];
    __shared__ int   rowIdx[32];
    __shared__ float wsum[4];

    const int t = threadIdx.x;
    const int lane = t & 63;
    const int w = t >> 6;                 // 0..3, this wave's K-slice
    const int quad = lane >> 4, l15 = lane & 15;
    const int rowBlk = blockIdx.x * 32;

    // ---- stage se into LDS (ds_read in loop instead of global load) ----
    {
        float4 s4 = ((const float4*)se)[t];
        *(float4*)&sse[4 * t] = s4;
    }

    // ---- A fragments: 2 M-tiles (rows rowBlk..rowBlk+31), in-register ----
    bf16x8 ah[2][2], al[2][2];
    #pragma unroll
    for (int mt = 0; mt < 2; ++mt) {
        #pragma unroll
        for (int ks = 0; ks < 2; ++ks) {
            const float4* ap = (const float4*)(x + (size_t)(rowBlk + mt * 16 + l15) * 64
                                               + ks * 32 + quad * 8);
            float4 a0 = ap[0], a1 = ap[1];
            float av[8] = {a0.x, a0.y, a0.z, a0.w, a1.x, a1.y, a1.z, a1.w};
            bf16x8 h, l;
            #pragma unroll
            for (int j = 0; j < 8; ++j) {
                unsigned short hb = f2bf(av[j]);
                h[j] = (short)hb;
                l[j] = (short)f2bf(av[j] - bf2f(hb));
            }
            ah[mt][ks] = h; al[mt][ks] = l;
        }
    }
    __syncthreads();   // sse ready

    float sb[2][4], sb2[2][4];
    int   si[2][4];
    #pragma unroll
    for (int mt = 0; mt < 2; ++mt)
        #pragma unroll
        for (int r = 0; r < 4; ++r) { sb[mt][r] = 3.4e38f; sb2[mt][r] = 3.4e38f; si[mt][r] = 0; }

    const int cbase = w * 256;

    // ---- named-slot 4-deep pipeline over 16 tiles ----
    // slot j holds tile (nt + j); body j consumes slot j then reloads it with
    // tile (nt + j + 4). Constant indices => named registers => per-slot waits.
    bf16x8 H0_0, H1_0, L0_0, L1_0;
    bf16x8 H0_1, H1_1, L0_1, L1_1;
    bf16x8 H0_2, H1_2, L0_2, L1_2;
    bf16x8 H0_3, H1_3, L0_3, L1_3;
    float sen0, sen1, sen2, sen3;

#define LOADSLOT(SUF, TILE)                                                     \
    {                                                                           \
        const int nl_ = cbase + (TILE) * 16 + l15;                              \
        const bf16x8* hp_ = (const bf16x8*)(ehT + (size_t)nl_ * 64 + quad * 8); \
        const bf16x8* lp_ = (const bf16x8*)(elT + (size_t)nl_ * 64 + quad * 8); \
        H0_##SUF = hp_[0]; H1_##SUF = hp_[4];                                   \
        L0_##SUF = lp_[0]; L1_##SUF = lp_[4];                                   \
        sen##SUF = sse[nl_];                                                    \
    }

    LOADSLOT(0, 0)
    LOADSLOT(1, 1)
    LOADSLOT(2, 2)
    LOADSLOT(3, 3)

#define BODY(SUF, TILE)                                                         \
    {                                                                           \
        const int code_ = cbase + (TILE) * 16 + l15;                            \
        bf16x8 ch0_ = H0_##SUF, ch1_ = H1_##SUF;                                \
        bf16x8 cl0_ = L0_##SUF, cl1_ = L1_##SUF;                                \
        float cse_ = sen##SUF;                                                  \
        LOADSLOT(SUF, (TILE) + 4)                                               \
        _Pragma("unroll")                                                       \
        for (int mt = 0; mt < 2; ++mt) {                                        \
            f32x4 aA = {0.f, 0.f, 0.f, 0.f}, aB = {0.f, 0.f, 0.f, 0.f};         \
            aA = __builtin_amdgcn_mfma_f32_16x16x32_bf16(ah[mt][0], ch0_, aA, 0, 0, 0); \
            aB = __builtin_amdgcn_mfma_f32_16x16x32_bf16(ah[mt][1], ch1_, aB, 0, 0, 0); \
            aA = __builtin_amdgcn_mfma_f32_16x16x32_bf16(ah[mt][0], cl0_, aA, 0, 0, 0); \
            aB = __builtin_amdgcn_mfma_f32_16x16x32_bf16(ah[mt][1], cl1_, aB, 0, 0, 0); \
            aA = __builtin_amdgcn_mfma_f32_16x16x32_bf16(al[mt][0], ch0_, aA, 0, 0, 0); \
            aB = __builtin_amdgcn_mfma_f32_16x16x32_bf16(al[mt][1], ch1_, aB, 0, 0, 0); \
            _Pragma("unroll")                                                   \
            for (int r = 0; r < 4; ++r) {                                       \
                float key = fmaf(-2.f, aA[r] + aB[r], cse_);                    \
                bool lt = key < sb[mt][r];                                      \
                sb2[mt][r] = fminf(sb2[mt][r], fmaxf(sb[mt][r], key));          \
                sb[mt][r]  = fminf(sb[mt][r], key);                             \
                si[mt][r]  = lt ? code_ : si[mt][r];                            \
            }                                                                   \
        }                                                                       \
    }

    for (int nt = 0; nt < 16; nt += 4) {
        BODY(0, nt + 0)
        BODY(1, nt + 1)
        BODY(2, nt + 2)
        BODY(3, nt + 3)
    }
    // prefetch tail (tiles 16..19) reads the 64-code pad region of ws: codes
    // up to 1087 < 1088 allocated — loaded but never consumed.
#undef BODY
#undef LOADSLOT

    // ---- exchange candidates: row-local = mt*16+quad*4+r, col = w*16+l15 ----
    const int col = w * 16 + l15;
    #pragma unroll
    for (int mt = 0; mt < 2; ++mt)
        #pragma unroll
        for (int r = 0; r < 4; ++r) {
            int rr = mt * 16 + quad * 4 + r;
            Lb [rr][col] = sb [mt][r];
            Lb2[rr][col] = sb2[mt][r];
            Li [rr][col] = si [mt][r];
        }
    __syncthreads();

    // ---- parallel per-row reduce: 8 threads per row, 8 cols each + shfl ----
    {
        const int r = t >> 3, seg = t & 7;
        const int c0 = seg * 8;
        float B = Lb[r][c0], B2 = Lb2[r][c0];
        int   I = Li[r][c0];
        #pragma unroll
        for (int c = 1; c < 8; ++c) {
            float b = Lb[r][c0 + c], b2 = Lb2[r][c0 + c];
            int i = Li[r][c0 + c];
            float nB2 = fminf(fminf(B2, b2), fmaxf(B, b));
            bool take = (b < B) || (b == B && i < I);
            B = take ? b : B;
            I = take ? i : I;
            B2 = nB2;
        }
        #pragma unroll
        for (int m = 1; m < 8; m <<= 1) {
            float ob  = __shfl_xor(B,  m, 64);
            float ob2 = __shfl_xor(B2, m, 64);
            int   oi  = __shfl_xor(I,  m, 64);
            float nB2 = fminf(fminf(B2, ob2), fmaxf(B, ob));
            bool take = (ob < B) || (ob == B && oi < I);
            B = take ? ob : B;
            I = take ? oi : I;
            B2 = nB2;
        }
        if (seg == 0) {
            rowIdx[r] = I;
            if (B2 - B < MARGIN) {
                int p = atomicAdd(cnt, 1);
                list[p] = make_int2(rowBlk + r, I);
            }
        }
    }
    __syncthreads();

    // ---- epilogue: thread t handles row t>>3, elems [(t&7)*8, +8) ----
    {
        const int r = t >> 3, c = (t & 7) * 8;
        const int idx = rowIdx[r];
        const float4* qrow = (const float4*)(eT + (size_t)idx * 64 + c);
        const float4* xrow = (const float4*)(x + (size_t)(rowBlk + r) * 64 + c);
        float4* orow = (float4*)(out + (size_t)(rowBlk + r) * 64 + c);
        float lsum = 0.f;
        #pragma unroll
        for (int i = 0; i < 2; ++i) {
            float4 q = qrow[i];
            float4 xv = xrow[i];
            float4 o;
            float dx;
            dx = q.x - xv.x; o.x = xv.x + dx; lsum = fmaf(dx, dx, lsum);
            dx = q.y - xv.y; o.y = xv.y + dx; lsum = fmaf(dx, dx, lsum);
            dx = q.z - xv.z; o.z = xv.z + dx; lsum = fmaf(dx, dx, lsum);
            dx = q.w - xv.w; o.w = xv.w + dx; lsum = fmaf(dx, dx, lsum);
            orow[i] = o;
        }
        #pragma unroll
        for (int off = 32; off > 0; off >>= 1)
            lsum += __shfl_down(lsum, off, 64);
        if (lane == 0) wsum[w] = lsum;
    }
    __syncthreads();
    if (t == 0)
        parts[blockIdx.x] = wsum[0] + wsum[1] + wsum[2] + wsum[3];  // no atomics
}

// ---------------------------------------------------------------------------
// Exact fp32 re-score of flagged rows (R9, validated) + loss finalize: the
// ticket-last block sums parts[1024] + recheck deltas and writes the scalar.
__launch_bounds__(256)
__global__ void vq_fix(const float* __restrict__ x,
                       const float* __restrict__ se,
                       const float* __restrict__ eT,
                       const int2* __restrict__ list,
                       const int* __restrict__ cnt,
                       const float* __restrict__ parts,
                       float* __restrict__ lossAcc,
                       int* __restrict__ done,
                       float* __restrict__ out) {
    __shared__ float xs[64];
    __shared__ float cb[256];
    __shared__ int   ci[256];
    __shared__ int   newIdxS;
    __shared__ int   lastS;
    const int t = threadIdx.x;
    const int n = *cnt;

    for (int i = blockIdx.x; i < n; i += gridDim.x) {
        int2 en = list[i];
        const int row = en.x, oldIdx = en.y;
        if (t < 64) xs[t] = x[(size_t)row * 64 + t];
        __syncthreads();

        float sx = 0.f;
        #pragma unroll
        for (int d = 0; d < 64; ++d) sx = fmaf(xs[d], xs[d], sx);

        const int k0 = t * 4;
        const float4* e0 = (const float4*)(eT + (size_t)(k0 + 0) * 64);
        const float4* e1 = (const float4*)(eT + (size_t)(k0 + 1) * 64);
        const float4* e2 = (const float4*)(eT + (size_t)(k0 + 2) * 64);
        const float4* e3 = (const float4*)(eT + (size_t)(k0 + 3) * 64);
        float dot0 = 0.f, dot1 = 0.f, dot2 = 0.f, dot3 = 0.f;
        #pragma unroll
        for (int i4 = 0; i4 < 16; ++i4) {
            float4 v0 = e0[i4], v1 = e1[i4], v2 = e2[i4], v3 = e3[i4];
            float xa = xs[4 * i4 + 0], xb = xs[4 * i4 + 1];
            float xc = xs[4 * i4 + 2], xd = xs[4 * i4 + 3];
            dot0 = fmaf(xa, v0.x, dot0); dot0 = fmaf(xb, v0.y, dot0);
            dot0 = fmaf(xc, v0.z, dot0); dot0 = fmaf(xd, v0.w, dot0);
            dot1 = fmaf(xa, v1.x, dot1); dot1 = fmaf(xb, v1.y, dot1);
            dot1 = fmaf(xc, v1.z, dot1); dot1 = fmaf(xd, v1.w, dot1);
            dot2 = fmaf(xa, v2.x, dot2); dot2 = fmaf(xb, v2.y, dot2);
            dot2 = fmaf(xc, v2.z, dot2); dot2 = fmaf(xd, v2.w, dot2);
            dot3 = fmaf(xa, v3.x, dot3); dot3 = fmaf(xb, v3.y, dot3);
            dot3 = fmaf(xc, v3.z, dot3); dot3 = fmaf(xd, v3.w, dot3);
        }
        float dd0 = (sx + se[k0 + 0]) - 2.0f * dot0;
        float dd1 = (sx + se[k0 + 1]) - 2.0f * dot1;
        float dd2 = (sx + se[k0 + 2]) - 2.0f * dot2;
        float dd3 = (sx + se[k0 + 3]) - 2.0f * dot3;
        float db = dd0; int di = k0;
        if (dd1 < db) { db = dd1; di = k0 + 1; }
        if (dd2 < db) { db = dd2; di = k0 + 2; }
        if (dd3 < db) { db = dd3; di = k0 + 3; }
        cb[t] = db; ci[t] = di;
        __syncthreads();

        if (t < 64) {
            float B = cb[t]; int I = ci[t];
            #pragma unroll
            for (int s = 64; s < 256; s += 64) {
                float b = cb[t + s]; int i2 = ci[t + s];
                bool take = (b < B) || (b == B && i2 < I);
                B = take ? b : B;
                I = take ? i2 : I;
            }
            #pragma unroll
            for (int m = 1; m < 64; m <<= 1) {
                float ob = __shfl_xor(B, m, 64);
                int   oi = __shfl_xor(I, m, 64);
                bool take = (ob < B) || (ob == B && oi < I);
                B = take ? ob : B;
                I = take ? oi : I;
            }
            if (t == 0) newIdxS = I;
        }
        __syncthreads();

        const int ni = newIdxS;
        if (ni != oldIdx) {
            if (t < 64) {
                float xv = xs[t];
                float qn = eT[(size_t)ni * 64 + t];
                float qo = eT[(size_t)oldIdx * 64 + t];
                float dn = qn - xv, dl = qo - xv;
                out[(size_t)row * 64 + t] = xv + dn;
                float delta = dn * dn - dl * dl;
                #pragma unroll
                for (int off = 32; off > 0; off >>= 1)
                    delta += __shfl_down(delta, off, 64);
                if (t == 0) atomicAdd(lossAcc, delta);
            }
        }
        __syncthreads();
    }

    // ---- ticket: last block sums parts + recheck deltas, writes loss ----
    if (t == 0) {
        __threadfence();
        int fin = atomicAdd(done, 1);
        lastS = (fin == FIXBLOCKS - 1) ? 1 : 0;
    }
    __syncthreads();
    if (lastS) {
        float4 p4 = ((const float4*)parts)[t];     // 256 x 4 = 1024 parts
        float s = (p4.x + p4.y) + (p4.z + p4.w);
        cb[t] = s;
        __syncthreads();
        if (t < 64) {
            float v = cb[t] + cb[t + 64] + cb[t + 128] + cb[t + 192];
            #pragma unroll
            for (int off = 32; off > 0; off >>= 1)
                v += __shfl_down(v, off, 64);
            if (t == 0) {
                float total = v + atomicAdd(lossAcc, 0.0f);  // + rare deltas
                float m = total / (float)NELEM;
                out[NELEM] = 0.25f * m + m;
            }
        }
    }
}

// ---------------------------------------------------------------------------
extern "C" void kernel_launch(void* const* d_in, const int* in_sizes, int n_in,
                              void* d_out, int out_size, void* d_ws, size_t ws_size,
                              hipStream_t stream) {
    const float* x = (const float*)d_in[0];
    const float* e = (const float*)d_in[1];
    float* out = (float*)d_out;
    float* ws  = (float*)d_ws;

    // ws layout (float offsets):
    //   [0..15]   ctrl: lossAcc, cnt, done, spare
    //   +64       se   [1088 used (64-code read pad); region to +1280]
    //   +1280     eT   [65536]
    //   +66816    ehT  [1088*64 ushort = 34816 f]
    //   +101632   elT  [1088*64 ushort = 34816 f]
    //   +136448   list [32768 int2 = 65536 f]
    //   +204800   parts[1024]
    float* lossAcc      = ws;
    int*   cnt          = (int*)(ws + 1);
    int*   done         = (int*)(ws + 2);
    float* se           = ws + 64;
    float* eT           = ws + 1280;
    unsigned short* ehT = (unsigned short*)(ws + 66816);
    unsigned short* elT = (unsigned short*)(ws + 101632);
    int2*  list         = (int2*)(ws + 136448);
    float* parts        = ws + 204800;

    vq_prep<<<64, 256, 0, stream>>>(e, se, eT, ehT, elT, (int*)ws);
    vq_main<<<MAINBLK, 256, 0, stream>>>(x, se, eT, ehT, elT, out, parts, cnt, list);
    vq_fix<<<FIXBLOCKS, 256, 0, stream>>>(x, se, eT, list, cnt, parts, lossAcc, done, out);
}

// Round 14
// 107.664 us; speedup vs baseline: 1.4026x; 1.4026x over previous
//
#include <hip/hip_runtime.h>
#include <hip/hip_bf16.h>

// VectorQuantizer: x [32768 x 64] fp32, e [64 x 1024] fp32.
// d_out = [out (2097152 f32) = x + (q-x), loss = 1.25*mean((q-x)^2)].
//
// R14 = R13's LDS-resident-codebook structure with the precision rebuilt:
// fp16 codebook (ulp(0.05)=3e-5 vs bf16's 2e-4 — R13's hi-only bf16 keys had
// sigma ~1e-3 vs MARGIN 3e-3 => wrong argmins) + two-term fp16 split of x in
// registers (xh+xl). Dropped term is only x*el (|el|<=1.5e-5): key error
// sigma ~1.3e-4, worst-row ~8e-4. MARGIN 4e-3 => error budget 2e-3 (~15
// sigma). Flagged rows (~2%) exactly re-scored in fp32 by the validated
// parallel vq_fix (R1 math bit-for-bit) which patches out/loss + finalizes.
// K-loop: barrier-free, 2 ds_read_b128 + 4 MFMA/iter, ~55-reg live set —
// immune to the 64-VGPR allocator ceiling that killed register-ring designs.

#define NROWS 32768
#define DDIM  64
#define KCODE 1024
#define NELEM (NROWS * DDIM)
#define MARGIN 4e-3f
#define FIXBLOCKS 256
#define MAINBLK 256          // 1 block/CU, 512 threads, 128 rows/block

typedef __attribute__((ext_vector_type(8))) _Float16 f16x8;
typedef __attribute__((ext_vector_type(4))) float f32x4;

static __device__ __forceinline__ unsigned short f2h(float v) {
    _Float16 h = (_Float16)v;
    unsigned short b;
    __builtin_memcpy(&b, &h, 2);
    return b;
}
static __device__ __forceinline__ void gload16(const void* g, void* l) {
    __builtin_amdgcn_global_load_lds(
        (const __attribute__((address_space(1))) void*)g,
        (__attribute__((address_space(3))) void*)l, 16, 0, 0);
}

// ---------------------------------------------------------------------------
// prep (64 blocks x 256): per block 16 codes. se[k] exact fp32 (ascending-d
// fmaf — must match vq_fix), eT[k][d] fp32, ehSw[k][*] fp16 with the
// 16B-chunk XOR swizzle (chunk ch of code k at slot ch^(k&7)) so the LDS
// image (bit-copied by global_load_lds) serves conflict-free ds_read_b128.
__global__ void vq_prep(const float* __restrict__ e,
                        float* __restrict__ se,
                        float* __restrict__ eT,
                        unsigned short* __restrict__ ehSw,
                        int* __restrict__ ctrl) {
    __shared__ float tile[64][17];
    const int t = threadIdx.x;
    const int k0 = blockIdx.x * 16;
    if (blockIdx.x == 0 && t < 4) ctrl[t] = 0;
    #pragma unroll
    for (int i = 0; i < 4; ++i) {
        int idx = i * 256 + t;
        int d = idx >> 4, kk = idx & 15;
        tile[d][kk] = e[d * KCODE + k0 + kk];
    }
    __syncthreads();
    if (t < 16) {
        float s = 0.f;
        #pragma unroll
        for (int d = 0; d < 64; ++d) { float v = tile[d][t]; s = fmaf(v, v, s); }
        se[k0 + t] = s;
    }
    const int kk = t >> 4;            // code 0..15 within block
    const int dg = (t & 15) * 4;      // dim group (4 elems)
    const int kg = k0 + kk;
    float v0 = tile[dg + 0][kk], v1 = tile[dg + 1][kk];
    float v2 = tile[dg + 2][kk], v3 = tile[dg + 3][kk];
    *(float4*)&eT[(size_t)kg * 64 + dg] = make_float4(v0, v1, v2, v3);
    const int sw = (((dg >> 3) ^ (kg & 7)) << 3) + (dg & 7);
    *(ushort4*)&ehSw[(size_t)kg * 64 + sw] =
        make_ushort4(f2h(v0), f2h(v1), f2h(v2), f2h(v3));
}

// ---------------------------------------------------------------------------
__launch_bounds__(512)
__global__ void vq_main(const float* __restrict__ x,
                        const float* __restrict__ se,
                        const float* __restrict__ eT,
                        const unsigned short* __restrict__ ehSw,
                        float* __restrict__ out,
                        float* __restrict__ parts,
                        int* __restrict__ cnt,
                        int2* __restrict__ list) {
    __shared__ unsigned short Beh[KCODE * 64];   // 128 KB, swizzled fp16 codebook
    __shared__ float sse[KCODE];                 // 4 KB
    __shared__ float wsum[8];

    const int t = threadIdx.x;          // 0..511
    const int lane = t & 63;
    const int w = t >> 6;               // wave 0..7
    const int quad = lane >> 4, l15 = lane & 15;
    const int rowBase = blockIdx.x * 128 + w * 16;   // wave owns 16 rows

    // ---- stage codebook (bit-copy of the swizzled global image) + se ----
    {
        const unsigned char* g = (const unsigned char*)ehSw;
        #pragma unroll
        for (int r = 0; r < 16; ++r)
            gload16(g + (size_t)(r * 512 + t) * 16, &Beh[(r * 512 + t) * 8]);
        float2 s2 = ((const float2*)se)[t];
        sse[2 * t + 0] = s2.x;
        sse[2 * t + 1] = s2.y;
    }

    // ---- A fragments (fp16 two-term split): row = l15, k = quad*8+ks*32+j ----
    f16x8 ah0, ah1, al0, al1;
    {
        const float4* ap0 = (const float4*)(x + (size_t)(rowBase + l15) * 64 + quad * 8);
        const float4* ap1 = (const float4*)(x + (size_t)(rowBase + l15) * 64 + 32 + quad * 8);
        float4 a0 = ap0[0], a1 = ap0[1], b0 = ap1[0], b1 = ap1[1];
        float av[8] = {a0.x, a0.y, a0.z, a0.w, a1.x, a1.y, a1.z, a1.w};
        float bv[8] = {b0.x, b0.y, b0.z, b0.w, b1.x, b1.y, b1.z, b1.w};
        f16x8 h0, h1, l0, l1;
        #pragma unroll
        for (int j = 0; j < 8; ++j) {
            _Float16 ha = (_Float16)av[j];
            _Float16 hb = (_Float16)bv[j];
            h0[j] = ha;
            h1[j] = hb;
            l0[j] = (_Float16)(av[j] - (float)ha);
            l1[j] = (_Float16)(bv[j] - (float)hb);
        }
        ah0 = h0; ah1 = h1; al0 = l0; al1 = l1;
    }
    __syncthreads();   // codebook + se resident; drains gload16 vmcnt

    // ---- barrier-free scan: 64 iters x 16 codes, all from LDS ----
    float sb[4], sb2[4];
    int   si[4];
    #pragma unroll
    for (int r = 0; r < 4; ++r) { sb[r] = 3.4e38f; sb2[r] = 3.4e38f; si[r] = 0; }

    const int slot0 = ((quad ^ (l15 & 7)) << 3);        // ks=0 chunk (elems)
    const int slot1 = (((quad + 4) ^ (l15 & 7)) << 3);  // ks=1 chunk

    #pragma unroll 4
    for (int nt = 0; nt < 64; ++nt) {
        const int code = nt * 16 + l15;
        f16x8 b0 = *(const f16x8*)&Beh[code * 64 + slot0];
        f16x8 b1 = *(const f16x8*)&Beh[code * 64 + slot1];
        float cse = sse[code];
        f32x4 aA = {0.f, 0.f, 0.f, 0.f}, aB = {0.f, 0.f, 0.f, 0.f};
        aA = __builtin_amdgcn_mfma_f32_16x16x32_f16(ah0, b0, aA, 0, 0, 0);
        aB = __builtin_amdgcn_mfma_f32_16x16x32_f16(ah1, b1, aB, 0, 0, 0);
        aA = __builtin_amdgcn_mfma_f32_16x16x32_f16(al0, b0, aA, 0, 0, 0);
        aB = __builtin_amdgcn_mfma_f32_16x16x32_f16(al1, b1, aB, 0, 0, 0);
        #pragma unroll
        for (int r = 0; r < 4; ++r) {
            float key = fmaf(-2.f, aA[r] + aB[r], cse);   // ~ se - 2*x·eh
            bool lt = key < sb[r];                 // strict: earliest code wins
            sb2[r] = fminf(sb2[r], fmaxf(sb[r], key));
            sb[r]  = fminf(sb[r], key);
            si[r]  = lt ? code : si[r];
        }
    }

    // ---- in-wave butterfly argmin over the 16 lanes of each quad ----
    #pragma unroll
    for (int m = 1; m < 16; m <<= 1) {
        #pragma unroll
        for (int r = 0; r < 4; ++r) {
            float ob  = __shfl_xor(sb[r],  m, 64);
            float ob2 = __shfl_xor(sb2[r], m, 64);
            int   oi  = __shfl_xor(si[r],  m, 64);
            float nb2 = fminf(fminf(sb2[r], ob2), fmaxf(sb[r], ob));
            bool take = (ob < sb[r]) || (ob == sb[r] && oi < si[r]);
            sb[r] = take ? ob : sb[r];
            si[r] = take ? oi : si[r];
            sb2[r] = nb2;
        }
    }

    // ---- flag ambiguous rows (exact fp32 re-score + patch in vq_fix) ----
    if (l15 == 0) {
        #pragma unroll
        for (int r = 0; r < 4; ++r) {
            if (sb2[r] - sb[r] < MARGIN) {
                int p = atomicAdd(cnt, 1);
                list[p] = make_int2(rowBase + quad * 4 + r, si[r]);
            }
        }
    }

    // ---- broadcast each row's idx to its epilogue lanes (R3-validated) ----
    int src = (l15 >> 2) << 4;
    int j0 = __shfl(si[0], src, 64);
    int j1 = __shfl(si[1], src, 64);
    int j2 = __shfl(si[2], src, 64);
    int j3 = __shfl(si[3], src, 64);
    int rsel = l15 & 3;
    int myidx = rsel == 0 ? j0 : (rsel == 1 ? j1 : (rsel == 2 ? j2 : j3));

    // ---- epilogue: lane -> row rowBase+l15, elems [quad*16, quad*16+16) ----
    {
        const float4* qrow = (const float4*)(eT + (size_t)myidx * 64 + quad * 16);
        const float4* xrow = (const float4*)(x + (size_t)(rowBase + l15) * 64 + quad * 16);
        float4* orow = (float4*)(out + (size_t)(rowBase + l15) * 64 + quad * 16);
        float lsum = 0.f;
        #pragma unroll
        for (int i = 0; i < 4; ++i) {
            float4 q = qrow[i];
            float4 xv = xrow[i];
            float4 o;
            float dx;
            dx = q.x - xv.x; o.x = xv.x + dx; lsum = fmaf(dx, dx, lsum);
            dx = q.y - xv.y; o.y = xv.y + dx; lsum = fmaf(dx, dx, lsum);
            dx = q.z - xv.z; o.z = xv.z + dx; lsum = fmaf(dx, dx, lsum);
            dx = q.w - xv.w; o.w = xv.w + dx; lsum = fmaf(dx, dx, lsum);
            orow[i] = o;
        }
        #pragma unroll
        for (int off = 32; off > 0; off >>= 1)
            lsum += __shfl_down(lsum, off, 64);
        if (lane == 0) wsum[w] = lsum;
    }
    __syncthreads();
    if (t == 0) {
        float s = 0.f;
        #pragma unroll
        for (int i = 0; i < 8; ++i) s += wsum[i];
        parts[blockIdx.x] = s;            // no global atomic chain
    }
}

// ---------------------------------------------------------------------------
// Exact fp32 re-score of flagged rows (validated R9 math) + patch out/loss.
// Ticket-last block sums parts[256] + deltas, writes the loss scalar.
__launch_bounds__(256)
__global__ void vq_fix(const float* __restrict__ x,
                       const float* __restrict__ se,
                       const float* __restrict__ eT,
                       const int2* __restrict__ list,
                       const int* __restrict__ cnt,
                       const float* __restrict__ parts,
                       float* __restrict__ lossAcc,
                       int* __restrict__ done,
                       float* __restrict__ out) {
    __shared__ float xs[64];
    __shared__ float cb[256];
    __shared__ int   ci[256];
    __shared__ int   newIdxS;
    __shared__ int   lastS;
    const int t = threadIdx.x;
    const int n = *cnt;

    for (int i = blockIdx.x; i < n; i += gridDim.x) {
        int2 en = list[i];
        const int row = en.x, oldIdx = en.y;
        if (t < 64) xs[t] = x[(size_t)row * 64 + t];
        __syncthreads();

        float sx = 0.f;
        #pragma unroll
        for (int d = 0; d < 64; ++d) sx = fmaf(xs[d], xs[d], sx);

        const int k0 = t * 4;
        const float4* e0 = (const float4*)(eT + (size_t)(k0 + 0) * 64);
        const float4* e1 = (const float4*)(eT + (size_t)(k0 + 1) * 64);
        const float4* e2 = (const float4*)(eT + (size_t)(k0 + 2) * 64);
        const float4* e3 = (const float4*)(eT + (size_t)(k0 + 3) * 64);
        float dot0 = 0.f, dot1 = 0.f, dot2 = 0.f, dot3 = 0.f;
        #pragma unroll
        for (int i4 = 0; i4 < 16; ++i4) {
            float4 v0 = e0[i4], v1 = e1[i4], v2 = e2[i4], v3 = e3[i4];
            float xa = xs[4 * i4 + 0], xb = xs[4 * i4 + 1];
            float xc = xs[4 * i4 + 2], xd = xs[4 * i4 + 3];
            dot0 = fmaf(xa, v0.x, dot0); dot0 = fmaf(xb, v0.y, dot0);
            dot0 = fmaf(xc, v0.z, dot0); dot0 = fmaf(xd, v0.w, dot0);
            dot1 = fmaf(xa, v1.x, dot1); dot1 = fmaf(xb, v1.y, dot1);
            dot1 = fmaf(xc, v1.z, dot1); dot1 = fmaf(xd, v1.w, dot1);
            dot2 = fmaf(xa, v2.x, dot2); dot2 = fmaf(xb, v2.y, dot2);
            dot2 = fmaf(xc, v2.z, dot2); dot2 = fmaf(xd, v2.w, dot2);
            dot3 = fmaf(xa, v3.x, dot3); dot3 = fmaf(xb, v3.y, dot3);
            dot3 = fmaf(xc, v3.z, dot3); dot3 = fmaf(xd, v3.w, dot3);
        }
        float dd0 = (sx + se[k0 + 0]) - 2.0f * dot0;
        float dd1 = (sx + se[k0 + 1]) - 2.0f * dot1;
        float dd2 = (sx + se[k0 + 2]) - 2.0f * dot2;
        float dd3 = (sx + se[k0 + 3]) - 2.0f * dot3;
        float db = dd0; int di = k0;
        if (dd1 < db) { db = dd1; di = k0 + 1; }
        if (dd2 < db) { db = dd2; di = k0 + 2; }
        if (dd3 < db) { db = dd3; di = k0 + 3; }
        cb[t] = db; ci[t] = di;
        __syncthreads();

        if (t < 64) {
            float B = cb[t]; int I = ci[t];
            #pragma unroll
            for (int s = 64; s < 256; s += 64) {
                float b = cb[t + s]; int i2 = ci[t + s];
                bool take = (b < B) || (b == B && i2 < I);
                B = take ? b : B;
                I = take ? i2 : I;
            }
            #pragma unroll
            for (int m = 1; m < 64; m <<= 1) {
                float ob = __shfl_xor(B, m, 64);
                int   oi = __shfl_xor(I, m, 64);
                bool take = (ob < B) || (ob == B && oi < I);
                B = take ? ob : B;
                I = take ? oi : I;
            }
            if (t == 0) newIdxS = I;
        }
        __syncthreads();

        const int ni = newIdxS;
        if (ni != oldIdx) {
            if (t < 64) {
                float xv = xs[t];
                float qn = eT[(size_t)ni * 64 + t];
                float qo = eT[(size_t)oldIdx * 64 + t];
                float dn = qn - xv, dl = qo - xv;
                out[(size_t)row * 64 + t] = xv + dn;
                float delta = dn * dn - dl * dl;
                #pragma unroll
                for (int off = 32; off > 0; off >>= 1)
                    delta += __shfl_down(delta, off, 64);
                if (t == 0) atomicAdd(lossAcc, delta);
            }
        }
        __syncthreads();
    }

    // ---- ticket: last block sums parts + recheck deltas, writes loss ----
    if (t == 0) {
        __threadfence();
        int fin = atomicAdd(done, 1);
        lastS = (fin == FIXBLOCKS - 1) ? 1 : 0;
    }
    __syncthreads();
    if (lastS) {
        cb[t] = parts[t];                 // 256 block partials
        __syncthreads();
        if (t < 64) {
            float v = cb[t] + cb[t + 64] + cb[t + 128] + cb[t + 192];
            #pragma unroll
            for (int off = 32; off > 0; off >>= 1)
                v += __shfl_down(v, off, 64);
            if (t == 0) {
                float total = v + atomicAdd(lossAcc, 0.0f);  // + rare deltas
                float m = total / (float)NELEM;
                out[NELEM] = 0.25f * m + m;
            }
        }
    }
}

// ---------------------------------------------------------------------------
extern "C" void kernel_launch(void* const* d_in, const int* in_sizes, int n_in,
                              void* d_out, int out_size, void* d_ws, size_t ws_size,
                              hipStream_t stream) {
    const float* x = (const float*)d_in[0];
    const float* e = (const float*)d_in[1];
    float* out = (float*)d_out;
    float* ws  = (float*)d_ws;

    // ws layout (float offsets):
    //   [0..15]   ctrl: lossAcc, cnt, done, spare
    //   +64       se   [1024]
    //   +1280     eT   [65536]
    //   +66816    ehSw [65536 ushort = 32768 f]  (swizzled fp16, LDS image)
    //   +99584    list [32768 int2 = 65536 f]
    //   +165120   parts[256]
    float* lossAcc       = ws;
    int*   cnt           = (int*)(ws + 1);
    int*   done          = (int*)(ws + 2);
    float* se            = ws + 64;
    float* eT            = ws + 1280;
    unsigned short* ehSw = (unsigned short*)(ws + 66816);
    int2*  list          = (int2*)(ws + 99584);
    float* parts         = ws + 165120;

    vq_prep<<<64, 256, 0, stream>>>(e, se, eT, ehSw, (int*)ws);
    vq_main<<<MAINBLK, 512, 0, stream>>>(x, se, eT, ehSw, out, parts, cnt, list);
    vq_fix<<<FIXBLOCKS, 256, 0, stream>>>(x, se, eT, list, cnt, parts, lossAcc, done, out);
}